// Round 7
// baseline (274.046 us; speedup 1.0000x reference)
//
#include <hip/hip_runtime.h>

// mIoU over int32 class maps, NUM=21 (values 0..21; class 0 excluded from iou).
// out[0]=mIoU, out[1..21]=iou for classes 1..21 (f32).
//
// R7: probe the read SERVICE RATE limiter. Reads go via global_load_lds
// (fire-and-forget DMA to LDS, no VGPR writeback) into per-wave PRIVATE
// double buffers -> no __syncthreads in the hot loop (vmcnt is per-wave).
// Manual s_waitcnt vmcnt(2)/vmcnt(0) + sched_barrier(0) orders stage->read.
// aux=2 = NT cache policy (matches R5's nt-load win). Joint 22x22 hist,
// 1 ds_add/elem, NREP=2 replicas (bank conflicts are intra-wave-op; replicas
// beyond trivial don't matter), global-atomic flush, memset + finalize.

#define NUMC  21
#define NBINS 22
#define JBINS (NBINS * NBINS)   // 484
#define RSTR  485
#define NREP  2
#define GRID  2048
#define TPB   256

typedef int iv4 __attribute__((ext_vector_type(4)));

#define GLDS(GP, LP) \
    __builtin_amdgcn_global_load_lds( \
        (const __attribute__((address_space(1))) void*)(GP), \
        (__attribute__((address_space(3))) void*)(LP), 16, 0, 2)

#define DS4(P, T)                                      \
    atomicAdd(&hh[(T).x * NBINS + (P).x], 1u);         \
    atomicAdd(&hh[(T).y * NBINS + (P).y], 1u);         \
    atomicAdd(&hh[(T).z * NBINS + (P).z], 1u);         \
    atomicAdd(&hh[(T).w * NBINS + (P).w], 1u);

__global__ void __launch_bounds__(256) hist_joint(
        const int* __restrict__ yp, const int* __restrict__ yt,
        unsigned int* __restrict__ g, int n) {
    __shared__ unsigned int hist[NREP * RSTR];                 // 3880 B
    __shared__ __align__(16) int stage[4 /*waves*/ * 4 * 256]; // 16384 B

    for (int i = threadIdx.x; i < NREP * RSTR; i += TPB) hist[i] = 0u;
    __syncthreads();

    const int lane = threadIdx.x & 63;
    const int wave = threadIdx.x >> 6;
    unsigned int* hh = hist + (wave >> 1) * RSTR;  // 2 waves share a replica

    const iv4* __restrict__ yp4 = (const iv4*)yp;
    const iv4* __restrict__ yt4 = (const iv4*)yt;
    const int n4 = n >> 2;
    const int stride = GRID * TPB;               // in int4 units
    const int i0 = blockIdx.x * TPB + threadIdx.x;
    const int iters = n4 / stride;

    if (iters * stride == n4 && (n & 3) == 0) {
        // fast path (exact fit: 8.39M = 16 * 2048 * 256)
        // per-wave staging: [buf][arr][lane] ; each buf+arr slab = 1 KB
        int* base = stage + wave * 1024;
        int* bp[2] = { base,       base + 512 };   // yp slabs (buf0, buf1)
        int* bt[2] = { base + 256, base + 768 };   // yt slabs

        // prologue: stage iter 0 into buf0
        GLDS(yp4 + i0, bp[0]);
        GLDS(yt4 + i0, bt[0]);

        for (int it = 0; it < iters; ++it) {
            const int b = it & 1;
            if (it + 1 < iters) {
                const int j = i0 + (it + 1) * stride;
                GLDS(yp4 + j, bp[b ^ 1]);
                GLDS(yt4 + j, bt[b ^ 1]);
                __builtin_amdgcn_s_waitcnt(0x0F72);  // vmcnt(2): current buf done
            } else {
                __builtin_amdgcn_s_waitcnt(0x0F70);  // vmcnt(0): drain
            }
            __builtin_amdgcn_sched_barrier(0);
            iv4 p = *((const iv4*)bp[b] + lane);
            iv4 t = *((const iv4*)bt[b] + lane);
            DS4(p, t)
        }
    } else {
        // generic fallback: nt loads, 1-deep rotation (R5 structure)
        if (i0 < n4) {
            iv4 p = __builtin_nontemporal_load(yp4 + i0);
            iv4 t = __builtin_nontemporal_load(yt4 + i0);
            for (int j = i0 + stride; j < n4; j += stride) {
                iv4 pn = __builtin_nontemporal_load(yp4 + j);
                iv4 tn = __builtin_nontemporal_load(yt4 + j);
                DS4(p, t)
                p = pn; t = tn;
            }
            DS4(p, t)
        }
        if (blockIdx.x == 0 && threadIdx.x == 0) {
            for (int k = n4 << 2; k < n; k++)
                atomicAdd(&hh[yt[k] * NBINS + yp[k]], 1u);
        }
    }

    __syncthreads();
    // flush: sum replicas, one global atomic per nonzero bin per block
    for (int c = threadIdx.x; c < JBINS; c += TPB) {
        unsigned int s = hist[c] + hist[RSTR + c];
        if (s) atomicAdd(&g[c], s);
    }
}

__global__ void finalize_kernel(const unsigned int* __restrict__ g,
                                float* __restrict__ out) {
    int lane = threadIdx.x;  // single wave of 64
    float iou = 0.0f, pres = 0.0f;
    if (lane >= 1 && lane <= NUMC) {
        unsigned int ct = 0, cp = 0;
        #pragma unroll
        for (int k = 0; k < NBINS; k++) {
            ct += g[lane * NBINS + k];   // row sum: cnt_true[lane]
            cp += g[k * NBINS + lane];   // col sum: cnt_pred[lane]
        }
        unsigned int ci = g[lane * NBINS + lane];
        float u = (float)ct + (float)cp - (float)ci;
        iou = ((float)ci + 1e-6f) / (u + 1e-6f);
        pres = (ct > 0u) ? 1.0f : 0.0f;
        out[lane] = iou;  // out[1..21]
    }
    float v = iou * pres, pc = pres;
    #pragma unroll
    for (int off = 32; off > 0; off >>= 1) {
        v += __shfl_down(v, off);
        pc += __shfl_down(pc, off);
    }
    if (lane == 0) out[0] = v / fmaxf(pc, 1.0f);
}

extern "C" void kernel_launch(void* const* d_in, const int* in_sizes, int n_in,
                              void* d_out, int out_size, void* d_ws, size_t ws_size,
                              hipStream_t stream) {
    const int* yp = (const int*)d_in[0];
    const int* yt = (const int*)d_in[1];
    int n = in_sizes[0];
    float* out = (float*)d_out;
    unsigned int* g = (unsigned int*)d_ws;  // 484 joint-bin counters

    hipMemsetAsync(g, 0, JBINS * sizeof(unsigned int), stream);
    hist_joint<<<GRID, TPB, 0, stream>>>(yp, yt, g, n);
    finalize_kernel<<<1, 64, 0, stream>>>(g, out);
}

// Round 8
// 257.187 us; speedup vs baseline: 1.0656x; 1.0656x over previous
//
#include <hip/hip_runtime.h>

// mIoU over int32 class maps, NUM=21 (values 0..21; class 0 excluded from iou).
// out[0]=mIoU, out[1..21]=iou for classes 1..21 (f32).
//
// R8: R5 structure (joint 22x22 hist, 1 ds_add/elem, per-wave LDS replicas,
// nt loads, non-atomic partials -> reduce -> finalize) with the read stream
// re-shaped: each WAVE owns a contiguous 2 KB chunk per array per sweep,
// fetched as two back-to-back perfectly-coalesced dwordx4 instructions
// (lane-contiguous within each), depth-2 rotation (8 KB in flight / wave).
// This is the access shape of the 6.9 TB/s fill, applied to reads.

#define NUMC  21
#define NBINS 22
#define JBINS (NBINS * NBINS)   // 484
#define RSTR  485               // odd replica stride: spreads banks
#define NREP  4                 // one replica per wave (256 threads)
#define GRID  2048
#define TPB   256

typedef int iv4 __attribute__((ext_vector_type(4)));

#define LDP(J) __builtin_nontemporal_load(yp4 + (J))
#define LDT(J) __builtin_nontemporal_load(yt4 + (J))
#define DS4(P, T)                                      \
    atomicAdd(&hh[(T).x * NBINS + (P).x], 1u);         \
    atomicAdd(&hh[(T).y * NBINS + (P).y], 1u);         \
    atomicAdd(&hh[(T).z * NBINS + (P).z], 1u);         \
    atomicAdd(&hh[(T).w * NBINS + (P).w], 1u);

__global__ void __launch_bounds__(256) hist_joint(
        const int* __restrict__ yp, const int* __restrict__ yt,
        unsigned int* __restrict__ partials, int n) {
    __shared__ unsigned int h[NREP * RSTR];
    for (int i = threadIdx.x; i < NREP * RSTR; i += TPB) h[i] = 0u;
    __syncthreads();

    const int lane = threadIdx.x & 63;
    const int wave = threadIdx.x >> 6;
    unsigned int* hh = h + wave * RSTR;  // replica per wave

    const iv4* __restrict__ yp4 = (const iv4*)yp;
    const iv4* __restrict__ yt4 = (const iv4*)yt;
    const int n4 = n >> 2;

    // wave-contiguous blocking: wave w covers int4 [w*128, w*128+128) per sweep
    const int gwave   = blockIdx.x * 4 + wave;      // wave id in grid
    const int nwaves  = GRID * 4;
    const int wstride = nwaves * 128;               // int4 per sweep
    const int sweeps  = n4 / wstride;

    if (sweeps * wstride == n4 && (n & 3) == 0) {
        // fast path (exact fit: 8,388,608 = 8 * 8192 * 128)
        const int j0 = gwave * 128 + lane;
        // prologue: sweep 0 in flight (4 KB/wave)
        iv4 pa = LDP(j0),      pb = LDP(j0 + 64);
        iv4 ta = LDT(j0),      tb = LDT(j0 + 64);
        for (int it = 1; it < sweeps; ++it) {
            const int j = j0 + it * wstride;
            iv4 npa = LDP(j),      npb = LDP(j + 64);   // next sweep (4 KB)
            iv4 nta = LDT(j),      ntb = LDT(j + 64);
            DS4(pa, ta) DS4(pb, tb)                     // consume current
            pa = npa; pb = npb; ta = nta; tb = ntb;
        }
        DS4(pa, ta) DS4(pb, tb)
    } else {
        // generic fallback: per-thread grid-stride, 1-deep rotation (R5)
        const int stride = GRID * TPB;
        const int i0 = blockIdx.x * TPB + threadIdx.x;
        if (i0 < n4) {
            iv4 p = LDP(i0), t = LDT(i0);
            for (int j = i0 + stride; j < n4; j += stride) {
                iv4 pn = LDP(j), tn = LDT(j);
                DS4(p, t)
                p = pn; t = tn;
            }
            DS4(p, t)
        }
        if (blockIdx.x == 0 && threadIdx.x == 0) {
            for (int k = n4 << 2; k < n; k++)
                atomicAdd(&hh[yt[k] * NBINS + yp[k]], 1u);
        }
    }
#undef DS4
#undef LDP
#undef LDT

    __syncthreads();
    // sum the 4 replicas, write this block's partial row (coalesced, no atomics)
    for (int c = threadIdx.x; c < JBINS; c += TPB) {
        unsigned int s = h[c] + h[RSTR + c] + h[2 * RSTR + c] + h[3 * RSTR + c];
        partials[(size_t)blockIdx.x * JBINS + c] = s;
    }
}

__global__ void __launch_bounds__(256) reduce_partials(
        const unsigned int* __restrict__ partials,
        unsigned int* __restrict__ g, int nblocks) {
    __shared__ unsigned int lds[256];
    const int c = blockIdx.x;  // one block per joint bin
    unsigned int s = 0;
    for (int b = threadIdx.x; b < nblocks; b += 256)
        s += partials[(size_t)b * JBINS + c];
    lds[threadIdx.x] = s;
    __syncthreads();
    for (int w = 128; w > 0; w >>= 1) {
        if (threadIdx.x < w) lds[threadIdx.x] += lds[threadIdx.x + w];
        __syncthreads();
    }
    if (threadIdx.x == 0) g[c] = lds[0];
}

__global__ void finalize_kernel(const unsigned int* __restrict__ g,
                                float* __restrict__ out) {
    int lane = threadIdx.x;  // single wave of 64
    float iou = 0.0f, pres = 0.0f;
    if (lane >= 1 && lane <= NUMC) {
        unsigned int ct = 0, cp = 0;
        #pragma unroll
        for (int k = 0; k < NBINS; k++) {
            ct += g[lane * NBINS + k];   // row sum: cnt_true[lane]
            cp += g[k * NBINS + lane];   // col sum: cnt_pred[lane]
        }
        unsigned int ci = g[lane * NBINS + lane];
        float u = (float)ct + (float)cp - (float)ci;
        iou = ((float)ci + 1e-6f) / (u + 1e-6f);
        pres = (ct > 0u) ? 1.0f : 0.0f;
        out[lane] = iou;  // out[1..21]
    }
    float v = iou * pres, pc = pres;
    #pragma unroll
    for (int off = 32; off > 0; off >>= 1) {
        v += __shfl_down(v, off);
        pc += __shfl_down(pc, off);
    }
    if (lane == 0) out[0] = v / fmaxf(pc, 1.0f);
}

extern "C" void kernel_launch(void* const* d_in, const int* in_sizes, int n_in,
                              void* d_out, int out_size, void* d_ws, size_t ws_size,
                              hipStream_t stream) {
    const int* yp = (const int*)d_in[0];
    const int* yt = (const int*)d_in[1];
    int n = in_sizes[0];
    float* out = (float*)d_out;

    // ws layout: g[484] | partials[GRID * 484]  (~4.0 MB)
    unsigned int* g = (unsigned int*)d_ws;
    unsigned int* partials = g + JBINS;

    hist_joint<<<GRID, TPB, 0, stream>>>(yp, yt, partials, n);
    reduce_partials<<<JBINS, 256, 0, stream>>>(partials, g, GRID);
    finalize_kernel<<<1, 64, 0, stream>>>(g, out);
}